// Round 1
// baseline (393.544 us; speedup 1.0000x reference)
//
#include <hip/hip_runtime.h>

typedef _Float16 h8 __attribute__((ext_vector_type(8)));
typedef _Float16 h4 __attribute__((ext_vector_type(4)));
typedef float f4 __attribute__((ext_vector_type(4)));

#define MFMA16(a, b, c) __builtin_amdgcn_mfma_f32_16x16x32_f16((a), (b), (c), 0, 0, 0)
#define AS1 __attribute__((address_space(1)))
#define AS3 __attribute__((address_space(3)))

static __device__ __forceinline__ void load_lds16(const _Float16* g, _Float16* l) {
  // async DMA: 16B per lane, LDS dest = wave-uniform base + lane*16 [m97]
  __builtin_amdgcn_global_load_lds((const AS1 void*)g, (AS3 void*)l, 16, 0, 0);
}

// ---------------- fp32 -> fp16 elementwise convert ----------------
__global__ __launch_bounds__(256) void cvt_f32_f16(const float* __restrict__ in,
                                                   _Float16* __restrict__ out, int n) {
  int i = (blockIdx.x * 256 + threadIdx.x) * 4;
  if (i < n) {
    const float4 v = *(const float4*)(in + i);
    h4 o;
    o[0] = (_Float16)v.x; o[1] = (_Float16)v.y; o[2] = (_Float16)v.z; o[3] = (_Float16)v.w;
    *(h4*)(out + i) = o;
  }
}

// ---------------- transpose+convert: W[K][N] f32 -> Wt[N][K] f16 ----------------
__global__ __launch_bounds__(256) void transpose_cvt(const float* __restrict__ W,
                                                     _Float16* __restrict__ Wt, int K, int N) {
  __shared__ _Float16 t[64][66];
  int n0 = blockIdx.x * 64, k0 = blockIdx.y * 64;
  int c = threadIdx.x & 63, r0 = threadIdx.x >> 6;
  for (int i = 0; i < 16; i++) {
    int r = r0 * 16 + i;
    t[r][c] = (_Float16)W[(size_t)(k0 + r) * N + n0 + c];
  }
  __syncthreads();
  for (int i = 0; i < 16; i++) {
    int r = r0 * 16 + i;
    Wt[(size_t)(n0 + r) * K + k0 + c] = t[c][r];
  }
}

// ---------------- GEMM: 128x256 tile, 512 thr (8 waves, 2Mx4N), BK=64 ----------------
// Depth-3 LDS ring (3 x [A 128x64 | B 256x64] = 144 KiB) with COUNTED vmcnt (T3+T4):
// stage slice t+2 at iter top; end of iter t does s_waitcnt vmcnt(6) (slice t+1's 6 loads
// are the oldest outstanding) THEN raw s_barrier. Per-wave wait + barrier => all waves'
// slice-(t+1) DMAs landed; 6 loads stay in flight across every barrier (never drain to 0).
// Buffer-overwrite safety: slot (t+2)%3 was last read in iter t-1, whose end barrier has
// already passed when iter t stages into it. Same 16B-chunk XOR swizzle as before
// (row&7 on staging q == read-side l16&7). MODE 0: QKV scatter via verified 128x136 LDS
// bounce, run twice (one per 128-col group); MODE 1: fp32 out.
template <int MODE>
__global__ __launch_bounds__(512, 2) void gemm_bt(const _Float16* __restrict__ A,
                                                  const _Float16* __restrict__ Bt,
                                                  const float* __restrict__ bias, int K,
                                                  _Float16* __restrict__ qp,
                                                  _Float16* __restrict__ kp,
                                                  _Float16* __restrict__ vtp,
                                                  float* __restrict__ outp, int N) {
  __shared__ __align__(16) _Float16 LDS[3][24576];  // 3 x (8192 A + 16384 B) f16 = 144 KiB
  const int m0 = blockIdx.y * 128, n0 = blockIdx.x * 256;
  const int tid = threadIdx.x;
  const int w = tid >> 6, lane = tid & 63, quad = lane >> 4, l16 = lane & 15;
  const int wmo = (w >> 2) * 64, wno = (w & 3) * 64;
  const int qq = lane >> 3, bb = lane & 7;
  const int lc8 = (bb ^ qq) * 8;  // swizzled k-chunk offset (f16)

  // staging: wave w owns A rows [w*16, w*16+16) (2 loads) and B rows [w*32, w*32+32) (4 loads)
  const _Float16* ap0 = A + (size_t)(m0 + w * 16 + qq) * K + lc8;
  const _Float16* bp0 = Bt + (size_t)(n0 + w * 32 + qq) * K + lc8;
  const int wA = w * 1024, wB = 8192 + w * 2048;

  f4 acc[4][4] = {};
  const int nk = K >> 6;

#define STAGE(slot, koff)                               \
  {                                                     \
    const _Float16* ap = ap0 + (koff);                  \
    const _Float16* bp = bp0 + (koff);                  \
    _Float16* la = &LDS[slot][wA];                      \
    _Float16* lb = &LDS[slot][wB];                      \
    load_lds16(ap, la);                                 \
    load_lds16(ap + (size_t)8 * K, la + 512);           \
    load_lds16(bp, lb);                                 \
    load_lds16(bp + (size_t)8 * K, lb + 512);           \
    load_lds16(bp + (size_t)16 * K, lb + 1024);         \
    load_lds16(bp + (size_t)24 * K, lb + 1536);         \
  }

  // prologue: slices 0,1 in flight (12 loads); wait slice 0 (own), barrier -> global
  STAGE(0, 0);
  STAGE(1, 64);
  asm volatile("s_waitcnt vmcnt(6)" ::: "memory");
  __builtin_amdgcn_s_barrier();

  int cb = 0, sb = 2;
  for (int t = 0; t < nk; ++t) {
    if (t + 2 < nk) STAGE(sb, (t + 2) * 64);
    sb = cb;  // slot freed after this iteration's barrier
    const _Float16* As = &LDS[cb][0];
    const _Float16* Bs = &LDS[cb][8192];
#pragma unroll
    for (int ks = 0; ks < 2; ks++) {
      h8 af[4], bf[4];
#pragma unroll
      for (int mi = 0; mi < 4; mi++) {
        const int r = wmo + mi * 16 + l16;
        const int pc = (ks * 4 + quad) ^ (l16 & 7);
        af[mi] = *(const h8*)(&As[r * 64 + pc * 8]);
      }
#pragma unroll
      for (int ni = 0; ni < 4; ni++) {
        const int r = wno + ni * 16 + l16;
        const int pc = (ks * 4 + quad) ^ (l16 & 7);
        bf[ni] = *(const h8*)(&Bs[r * 64 + pc * 8]);
      }
      __builtin_amdgcn_s_setprio(1);
#pragma unroll
      for (int mi = 0; mi < 4; mi++)
#pragma unroll
        for (int ni = 0; ni < 4; ni++) acc[mi][ni] = MFMA16(af[mi], bf[ni], acc[mi][ni]);
      __builtin_amdgcn_s_setprio(0);
    }
    if (t + 1 < nk) {
      if (t + 2 < nk)
        asm volatile("s_waitcnt vmcnt(6)" ::: "memory");  // slice t+1 landed; t+2 in flight
      else
        asm volatile("s_waitcnt vmcnt(0)" ::: "memory");  // tail
      __builtin_amdgcn_s_barrier();
    }
    cb = (cb == 2) ? 0 : cb + 1;
  }
#undef STAGE

  // ---- Epilogue. C element (row = quad*4+r, col = l16) per 16x16 tile [m89-verified]. ----
  if constexpr (MODE == 0) {
    _Float16* U = &LDS[0][0];  // 128 x 136 bounce (34816 B, fits in slot 0)
    const int which = n0 >> 11;  // 256-wide tile never straddles q/k/v (boundaries % 2048)
    const int bq = m0 >> 11, ms = m0 & 2047;
    const int wn_ = w & 3;
    const int grp = wn_ >> 1, cl = (wn_ & 1) * 64;
    for (int g = 0; g < 2; ++g) {  // two 128-col groups -> heads hh, hh+1
      __syncthreads();
      if (grp == g) {
        if (which == 2) {
#pragma unroll
          for (int mi = 0; mi < 4; mi++)
#pragma unroll
            for (int ni = 0; ni < 4; ni++) {
              const int d = cl + ni * 16 + l16;
              const float bv = bias[n0 + g * 128 + d];
              const int s0 = wmo + mi * 16 + quad * 4;
              h4 pack;
#pragma unroll
              for (int r = 0; r < 4; r++) pack[r] = (_Float16)(acc[mi][ni][r] + bv);
              *(h4*)(&U[d * 136 + s0]) = pack;  // transposed: U[d][s]
            }
        } else {
#pragma unroll
          for (int mi = 0; mi < 4; mi++)
#pragma unroll
            for (int ni = 0; ni < 4; ni++) {
              const int d = cl + ni * 16 + l16;
              const float bv = bias[n0 + g * 128 + d];
#pragma unroll
              for (int r = 0; r < 4; r++) {
                const int s = wmo + mi * 16 + quad * 4 + r;
                U[s * 136 + d] = (_Float16)(acc[mi][ni][r] + bv);
              }
            }
        }
      }
      __syncthreads();
      const int hh = ((n0 + g * 128) >> 7) & 15;
      const size_t hb = (size_t)bq * 16 + hh;
      if (which == 2) {
        _Float16* dst = vtp + hb * (size_t)(128 * 2048) + ms;
#pragma unroll
        for (int i = 0; i < 4; i++) {
          int f = i * 512 + tid, row = f >> 4, ch = f & 15;
          *(h8*)(dst + (size_t)row * 2048 + ch * 8) = *(h8*)(&U[row * 136 + ch * 8]);
        }
      } else {
        _Float16* dst = (which == 0 ? qp : kp) + (hb * 2048 + ms) * (size_t)128;
#pragma unroll
        for (int i = 0; i < 4; i++) {
          int f = i * 512 + tid, row = f >> 4, ch = f & 15;
          *(h8*)(dst + (size_t)row * 128 + ch * 8) = *(h8*)(&U[row * 136 + ch * 8]);
        }
      }
    }
  } else {
#pragma unroll
    for (int mi = 0; mi < 4; mi++)
#pragma unroll
      for (int ni = 0; ni < 4; ni++) {
        const int gm = m0 + wmo + mi * 16 + quad * 4;
        const int gn = n0 + wno + ni * 16 + l16;
        const float bv = bias[gn];
#pragma unroll
        for (int r = 0; r < 4; r++) outp[(size_t)(gm + r) * N + gn] = acc[mi][ni][r] + bv;
      }
  }
}

// ---------------- fused causal ALiBi attention ----------------
// grid (32 bh, 16 px): 512 uniform blocks (2/CU, 2 waves/SIMD); same-(b,h) blocks share an
// XCD (linear id mod 8 = bh mod 8) so K/V re-reads hit that XCD's L2.
// Block: 4 waves x 16 q-rows = 64-row tile; pairs {31-px, px} -> 33 j-iters each.
// K/V async-DMA double-buffered (1 barrier/iter, latency hidden under compute).
// ALiBi as column bias slope*j (row term -slope*i cancels in softmax); causal mask only on
// the diagonal tile. Row-sum l via a ones-column MFMA tile (o[8]).
__global__ __launch_bounds__(256, 2) void attn_kernel(const _Float16* __restrict__ Q,
                                                      const _Float16* __restrict__ Kg,
                                                      const _Float16* __restrict__ Vt,
                                                      _Float16* __restrict__ ctx) {
  __shared__ _Float16 Ks[2][8192];   // 64 rows x 128, 16B-chunk XOR swizzle p = lc ^ (row&7)
  __shared__ _Float16 Vs[2][8192];   // 128 rows x 64, same swizzle
  __shared__ _Float16 Vones[1088];   // [16][68]: row 0 = ones (l-accumulator B-tile)
  __shared__ _Float16 Pl[4][16 * 68];  // per-wave P round-trip; stride 68 -> conflict-free

  const int bh = blockIdx.x, px = blockIdx.y;
  const int b = bh >> 4, h = bh & 15;
  const int tid = threadIdx.x, w = tid >> 6, lane = tid & 63, quad = lane >> 4, l16 = lane & 15;
  const size_t hbo = (size_t)bh * (2048 * 128);
  const _Float16* Qh = Q + hbo;
  const _Float16* Kh = Kg + hbo;
  const _Float16* Vh = Vt + hbo;
  const float slope = exp2f(-0.5f * (float)h);
  const float L2E = 1.44269504088896f;
  const float NEG = -3.0e38f;

  for (int i = tid; i < 1088; i += 256) Vones[i] = (_Float16)0.f;
  if (tid < 64) Vones[tid] = (_Float16)1.f;  // row 0, cols 0..63

  float cj[4];
  for (int jf = 0; jf < 4; jf++) cj[jf] = slope * (float)(jf * 16 + l16);

  // staging constants: K slot s=c*64+lane -> row=4c+quad, lc=l16^((c&1)*4+quad)
  //                    V slot s=c*64+lane -> row=8c+(lane>>3), lc=(lane&7)^(lane>>3)
  const int kle = (l16 ^ quad) * 8, klo = kle ^ 32;
  const int lq = lane >> 3, vlc = ((lane & 7) ^ lq) * 8;

  for (int phase = 0; phase < 2; phase++) {
    const int t = phase ? px : 31 - px;
    const int qbase = t * 64 + w * 16;

    h8 aq[4];  // Q A-frags: A[m=l16][k=quad*8+j] [m120-verified]
#pragma unroll
    for (int t4 = 0; t4 < 4; t4++)
      aq[t4] = *(const h8*)(Qh + (size_t)(qbase + l16) * 128 + t4 * 32 + quad * 8);

    f4 o[9] = {};  // o[0..7] = output tiles, o[8] = row-sum (ones column)
    float m_i[4];
    for (int r = 0; r < 4; r++) m_i[r] = NEG;

    const int jtiles = t + 1;
    __syncthreads();  // previous phase's buffer readers (and Vones init) done
    // stage tile 0 -> buf 0 (waves 0,1: K; waves 2,3: V)
    if (w < 2) {
      const _Float16* kb = Kh + (size_t)(32 * w + quad) * 128;
      _Float16* dst = &Ks[0][w * 4096];
#pragma unroll
      for (int cc = 0; cc < 8; cc++)
        load_lds16(kb + (size_t)(4 * cc) * 128 + ((cc & 1) ? klo : kle), dst + cc * 512);
    } else {
      const _Float16* vb = Vh + (size_t)(64 * (w - 2) + lq) * 2048 + vlc;
      _Float16* dst = &Vs[0][(w - 2) * 4096];
#pragma unroll
      for (int cc = 0; cc < 8; cc++) load_lds16(vb + (size_t)(8 * cc) * 2048, dst + cc * 512);
    }

    for (int jt = 0; jt < jtiles; jt++) {
      const int j0 = jt * 64, cur = jt & 1;
      __syncthreads();  // buf[cur] staged (each wave drains vmcnt before barrier)
      if (jt + 1 < jtiles) {  // async-stage next tile into back buffer
        const int nj0 = j0 + 64, nb = cur ^ 1;
        if (w < 2) {
          const _Float16* kb = Kh + (size_t)(nj0 + 32 * w + quad) * 128;
          _Float16* dst = &Ks[nb][w * 4096];
#pragma unroll
          for (int cc = 0; cc < 8; cc++)
            load_lds16(kb + (size_t)(4 * cc) * 128 + ((cc & 1) ? klo : kle), dst + cc * 512);
        } else {
          const _Float16* vb = Vh + (size_t)(64 * (w - 2) + lq) * 2048 + nj0 + vlc;
          _Float16* dst = &Vs[nb][(w - 2) * 4096];
#pragma unroll
          for (int cc = 0; cc < 8; cc++) load_lds16(vb + (size_t)(8 * cc) * 2048, dst + cc * 512);
        }
      }
      // S = Q K^T (B-frag from swizzled Ks)
      f4 sc[4] = {};
#pragma unroll
      for (int jf = 0; jf < 4; jf++) {
        const int row = jf * 16 + l16;
#pragma unroll
        for (int t4 = 0; t4 < 4; t4++) {
          const int p = (t4 * 4 + quad) ^ (l16 & 7);
          h8 bk = *(const h8*)(&Ks[cur][row * 128 + p * 8]);
          sc[jf] = MFMA16(aq[t4], bk, sc[jf]);
        }
      }
      // ALiBi column bias
      const float bj0 = slope * (float)j0;
#pragma unroll
      for (int jf = 0; jf < 4; jf++) {
        const float cb = bj0 + cj[jf];
#pragma unroll
        for (int r = 0; r < 4; r++) sc[jf][r] += cb;
      }
      if (jt == jtiles - 1) {  // diagonal tile: causal mask
#pragma unroll
        for (int jf = 0; jf < 4; jf++) {
          const int j = j0 + jf * 16 + l16;
#pragma unroll
          for (int r = 0; r < 4; r++)
            if (j > qbase + quad * 4 + r) sc[jf][r] = NEG;
        }
      }
      // online softmax (max only; sum rides in o[8])
      float m_new[4], alpha[4];
#pragma unroll
      for (int r = 0; r < 4; r++) {
        float v = fmaxf(fmaxf(sc[0][r], sc[1][r]), fmaxf(sc[2][r], sc[3][r]));
        v = fmaxf(v, __shfl_xor(v, 1));
        v = fmaxf(v, __shfl_xor(v, 2));
        v = fmaxf(v, __shfl_xor(v, 4));
        v = fmaxf(v, __shfl_xor(v, 8));
        m_new[r] = fmaxf(m_i[r], v);
        alpha[r] = exp2f((m_i[r] - m_new[r]) * L2E);
        m_i[r] = m_new[r];
      }
#pragma unroll
      for (int jf = 0; jf < 4; jf++)
#pragma unroll
        for (int r = 0; r < 4; r++) sc[jf][r] = exp2f((sc[jf][r] - m_new[r]) * L2E);
#pragma unroll
      for (int nt = 0; nt < 9; nt++)
#pragma unroll
        for (int r = 0; r < 4; r++) o[nt][r] *= alpha[r];
      // P: C-layout -> A-layout via per-wave LDS (stride 68: conflict-free writes)
#pragma unroll
      for (int jf = 0; jf < 4; jf++)
#pragma unroll
        for (int r = 0; r < 4; r++)
          Pl[w][(quad * 4 + r) * 68 + jf * 16 + l16] = (_Float16)sc[jf][r];
      asm volatile("s_waitcnt lgkmcnt(0)" ::: "memory");
      h8 ap0 = *(const h8*)(&Pl[w][l16 * 68 + quad * 8]);
      h8 ap1 = *(const h8*)(&Pl[w][l16 * 68 + 32 + quad * 8]);
      // O += P V (B-frag from swizzled Vs) + ones-tile for l
#pragma unroll
      for (int nt = 0; nt < 8; nt++) {
        const int row = nt * 16 + l16;
        const int p0 = quad ^ (l16 & 7), p1 = (4 + quad) ^ (l16 & 7);
        h8 bv0 = *(const h8*)(&Vs[cur][row * 64 + p0 * 8]);
        h8 bv1 = *(const h8*)(&Vs[cur][row * 64 + p1 * 8]);
        o[nt] = MFMA16(ap0, bv0, o[nt]);
        o[nt] = MFMA16(ap1, bv1, o[nt]);
      }
      {
        h8 b0 = *(const h8*)(&Vones[l16 * 68 + quad * 8]);
        h8 b1 = *(const h8*)(&Vones[l16 * 68 + 32 + quad * 8]);
        o[8] = MFMA16(ap0, b0, o[8]);
        o[8] = MFMA16(ap1, b1, o[8]);
      }
    }

    // epilogue: l = o[8] col 0 (broadcast within quad), normalize, write ctx
#pragma unroll
    for (int r = 0; r < 4; r++) {
      float lsum = __shfl(o[8][r], lane & 48);
      float inv = 1.0f / lsum;
      const int i = qbase + quad * 4 + r;
      const size_t row = (size_t)b * 2048 + i;
#pragma unroll
      for (int nt = 0; nt < 8; nt++)
        ctx[row * 2048 + h * 128 + nt * 16 + l16] = (_Float16)(o[nt][r] * inv);
    }
  }
}

extern "C" void kernel_launch(void* const* d_in, const int* in_sizes, int n_in, void* d_out,
                              int out_size, void* d_ws, size_t ws_size, hipStream_t stream) {
  const float* x = (const float*)d_in[0];      // [2,2048,2048]
  const float* qkv_w = (const float*)d_in[1];  // [2048,6144]
  const float* qkv_b = (const float*)d_in[2];  // [6144]
  const float* out_w = (const float*)d_in[3];  // [2048,2048]
  const float* out_b = (const float*)d_in[4];  // [2048]
  float* out = (float*)d_out;                  // [4096,2048] f32

  char* ws = (char*)d_ws;
  if (ws_size < 117440512u) return;  // need 112 MiB
  _Float16* xb  = (_Float16*)(ws + 0);          // 16 MiB  [4096][2048]
  _Float16* wqt = (_Float16*)(ws + 16777216);   // 24 MiB  [6144][2048]
  _Float16* wot = (_Float16*)(ws + 41943040);   // 8 MiB   [2048][2048]
  _Float16* q   = (_Float16*)(ws + 50331648);   // 16 MiB  [b,h,s,d]
  _Float16* k   = (_Float16*)(ws + 67108864);   // 16 MiB  [b,h,s,d]
  _Float16* vt  = (_Float16*)(ws + 83886080);   // 16 MiB  [b,h,d,s]
  _Float16* ctx = (_Float16*)(ws + 100663296);  // 16 MiB  [4096][2048]

  cvt_f32_f16<<<8192, 256, 0, stream>>>(x, xb, 8388608);
  transpose_cvt<<<dim3(96, 32), 256, 0, stream>>>(qkv_w, wqt, 2048, 6144);
  transpose_cvt<<<dim3(32, 32), 256, 0, stream>>>(out_w, wot, 2048, 2048);
  gemm_bt<0><<<dim3(24, 32), 512, 0, stream>>>(xb, wqt, qkv_b, 2048, q, k, vt, nullptr, 6144);
  attn_kernel<<<dim3(32, 16), 256, 0, stream>>>(q, k, vt, ctx);
  gemm_bt<1><<<dim3(8, 32), 512, 0, stream>>>(ctx, wot, out_b, 2048, nullptr, nullptr, nullptr,
                                              out, 2048);
}

// Round 3
// 391.762 us; speedup vs baseline: 1.0045x; 1.0045x over previous
//
#include <hip/hip_runtime.h>

typedef _Float16 h8 __attribute__((ext_vector_type(8)));
typedef _Float16 h4 __attribute__((ext_vector_type(4)));
typedef float f4 __attribute__((ext_vector_type(4)));

#define MFMA16(a, b, c) __builtin_amdgcn_mfma_f32_16x16x32_f16((a), (b), (c), 0, 0, 0)
#define AS1 __attribute__((address_space(1)))
#define AS3 __attribute__((address_space(3)))

static __device__ __forceinline__ void load_lds16(const _Float16* g, _Float16* l) {
  // async DMA: 16B per lane, LDS dest = wave-uniform base + lane*16 [m97]
  __builtin_amdgcn_global_load_lds((const AS1 void*)g, (AS3 void*)l, 16, 0, 0);
}

// ---------------- fp32 -> fp16 elementwise convert ----------------
__global__ __launch_bounds__(256) void cvt_f32_f16(const float* __restrict__ in,
                                                   _Float16* __restrict__ out, int n) {
  int i = (blockIdx.x * 256 + threadIdx.x) * 4;
  if (i < n) {
    const float4 v = *(const float4*)(in + i);
    h4 o;
    o[0] = (_Float16)v.x; o[1] = (_Float16)v.y; o[2] = (_Float16)v.z; o[3] = (_Float16)v.w;
    *(h4*)(out + i) = o;
  }
}

// ---------------- transpose+convert: W[K][N] f32 -> Wt[N][K] f16 ----------------
__global__ __launch_bounds__(256) void transpose_cvt(const float* __restrict__ W,
                                                     _Float16* __restrict__ Wt, int K, int N) {
  __shared__ _Float16 t[64][66];
  int n0 = blockIdx.x * 64, k0 = blockIdx.y * 64;
  int c = threadIdx.x & 63, r0 = threadIdx.x >> 6;
  for (int i = 0; i < 16; i++) {
    int r = r0 * 16 + i;
    t[r][c] = (_Float16)W[(size_t)(k0 + r) * N + n0 + c];
  }
  __syncthreads();
  for (int i = 0; i < 16; i++) {
    int r = r0 * 16 + i;
    Wt[(size_t)(n0 + r) * K + k0 + c] = t[c][r];
  }
}

// ---------------- GEMM: 128x256 tile, 512 thr (8 waves 2Mx4N), BK=64 ----------------
// Counted-vmcnt phase pipeline (T3+T4+T5), derived waits (provable, no drain in loop):
//   per K-tile T (buf = T&1), two phases:
//   P0: issue A(T+1) DMA (other buf; its old content last read at P1 of T-1, barrier-sep);
//       ds_read ALL bf (8) + afLo (4); 16 MFMA (mi 0-1); barrier.
//       -> B-region of buf free after P0.
//   P1: issue B(T+2) DMA (this buf's B-region, freed at P0 barrier);
//       ds_read afHi (4); 16 MFMA (mi 2-3); s_waitcnt vmcnt(4); barrier.
//       -> A-region free after P1.
//   Wait proof: per-wave issue order ... A(T+1)[2 loads], B(T+2)[4 loads]. vmcnt(4) at end
//   of T leaves exactly B(T+2) in flight; A(T+1) (4 back) and B(T+1) (8 back) are retired,
//   which is precisely what T+1's P0 reads. Loads stay in flight across barriers for ~1.5
//   iterations; only the last two K-tiles drain. Prologue: A(0),B(0),B(1) then vmcnt(4).
// Same 16B-chunk XOR swizzle (stage: src chunk = (lane&7)^(lane>>3); read: pc = k ^ (row&7)).
// MODE 0: QKV scatter via 128x136 LDS bounce per 128-col head group; MODE 1: fp32 out.
template <int MODE>
__global__ __launch_bounds__(512, 2) void gemm_pipe(const _Float16* __restrict__ A,
                                                    const _Float16* __restrict__ Bt,
                                                    const float* __restrict__ bias, int K,
                                                    _Float16* __restrict__ qp,
                                                    _Float16* __restrict__ kp,
                                                    _Float16* __restrict__ vtp,
                                                    float* __restrict__ outp, int N) {
  __shared__ __align__(16) _Float16 SH[49152];  // 2 bufs x (A 128x64 | B 256x64) = 96 KiB
  const int m0 = blockIdx.y * 128, n0 = blockIdx.x * 256;
  const int tid = threadIdx.x;
  const int w = tid >> 6, lane = tid & 63, quad = lane >> 4, l16 = lane & 15;
  const int wm = (w >> 2) * 64, wn = (w & 3) * 64;
  const int lq8 = lane >> 3, bb = lane & 7;
  const int lc8 = (bb ^ lq8) * 8;  // pre-swizzled source k-chunk (f16 offset)

  // staging ownership: wave w = A rows [w*16,w*16+16) (2 loads), B rows [w*32,w*32+32) (4)
  const _Float16* apr = A + (size_t)(m0 + w * 16 + lq8) * K + lc8;
  const _Float16* bpr = Bt + (size_t)(n0 + w * 32 + lq8) * K + lc8;
  const int NT = K >> 6;

  f4 acc[4][4] = {};

#define STG_A(t)                                                   \
  {                                                                \
    _Float16* d0 = SH + ((t) & 1) * 24576 + (w * 16) * 64;         \
    const _Float16* s0p = apr + (size_t)(t) * 64;                  \
    load_lds16(s0p, d0);                                           \
    load_lds16(s0p + (size_t)8 * K, d0 + 512);                     \
  }
#define STG_B(t)                                                   \
  {                                                                \
    _Float16* d0 = SH + ((t) & 1) * 24576 + 8192 + (w * 32) * 64;  \
    const _Float16* s0p = bpr + (size_t)(t) * 64;                  \
    load_lds16(s0p, d0);                                           \
    load_lds16(s0p + (size_t)8 * K, d0 + 512);                     \
    load_lds16(s0p + (size_t)16 * K, d0 + 1024);                   \
    load_lds16(s0p + (size_t)24 * K, d0 + 1536);                   \
  }

  // prologue: A(0),B(0) must land before T=0; B(1) may stay in flight
  STG_A(0);
  STG_B(0);
  STG_B(1);
  asm volatile("s_waitcnt vmcnt(4)" ::: "memory");
  __builtin_amdgcn_s_barrier();
  asm volatile("" ::: "memory");

  for (int T = 0; T < NT; ++T) {
    const _Float16* As = SH + (T & 1) * 24576;
    const _Float16* Bs = As + 8192;
    // ---- phase 0: stage A(T+1); compute mi 0-1 over all ni ----
    if (T + 1 < NT) STG_A(T + 1);
    h8 bf[4][2], af[2][2];
#pragma unroll
    for (int ni = 0; ni < 4; ni++)
#pragma unroll
      for (int ks = 0; ks < 2; ks++) {
        const int r = wn + ni * 16 + l16;
        const int pc = (ks * 4 + quad) ^ (l16 & 7);
        bf[ni][ks] = *(const h8*)(&Bs[r * 64 + pc * 8]);
      }
#pragma unroll
    for (int mi = 0; mi < 2; mi++)
#pragma unroll
      for (int ks = 0; ks < 2; ks++) {
        const int r = wm + mi * 16 + l16;
        const int pc = (ks * 4 + quad) ^ (l16 & 7);
        af[mi][ks] = *(const h8*)(&As[r * 64 + pc * 8]);
      }
    __builtin_amdgcn_s_setprio(1);
#pragma unroll
    for (int ks = 0; ks < 2; ks++)
#pragma unroll
      for (int mi = 0; mi < 2; mi++)
#pragma unroll
        for (int ni = 0; ni < 4; ni++) acc[mi][ni] = MFMA16(af[mi][ks], bf[ni][ks], acc[mi][ni]);
    __builtin_amdgcn_s_setprio(0);
    asm volatile("" ::: "memory");
    __builtin_amdgcn_s_barrier();
    asm volatile("" ::: "memory");
    // ---- phase 1: stage B(T+2); compute mi 2-3 (bf reused from P0) ----
    if (T + 2 < NT) STG_B(T + 2);
#pragma unroll
    for (int mi = 0; mi < 2; mi++)
#pragma unroll
      for (int ks = 0; ks < 2; ks++) {
        const int r = wm + 32 + mi * 16 + l16;
        const int pc = (ks * 4 + quad) ^ (l16 & 7);
        af[mi][ks] = *(const h8*)(&As[r * 64 + pc * 8]);
      }
    __builtin_amdgcn_s_setprio(1);
#pragma unroll
    for (int ks = 0; ks < 2; ks++)
#pragma unroll
      for (int mi = 0; mi < 2; mi++)
#pragma unroll
        for (int ni = 0; ni < 4; ni++)
          acc[2 + mi][ni] = MFMA16(af[mi][ks], bf[ni][ks], acc[2 + mi][ni]);
    __builtin_amdgcn_s_setprio(0);
    if (T + 2 < NT)
      asm volatile("s_waitcnt vmcnt(4)" ::: "memory");  // keep B(T+2) in flight
    else
      asm volatile("s_waitcnt vmcnt(0)" ::: "memory");  // tail drain
    __builtin_amdgcn_s_barrier();
    asm volatile("" ::: "memory");
  }
#undef STG_A
#undef STG_B

  // ---- Epilogue. C element (row = quad*4+r, col = l16) per 16x16 tile [m89-verified]. ----
  if constexpr (MODE == 0) {
    __syncthreads();
    _Float16* U = SH;  // 128 x 136 bounce (34816 B)
    const int which = n0 >> 11;  // 256-tile never straddles q/k/v (boundaries % 2048 == 0)
    const int bq = m0 >> 11, ms = m0 & 2047;
    const int wc = w & 3;
#pragma unroll
    for (int g = 0; g < 2; ++g) {  // two 128-col head groups
      if (g) __syncthreads();      // group-0 copies done before overwrite
      if ((wc >> 1) == g) {
        const int cl = (wc & 1) * 64;
        if (which == 2) {
#pragma unroll
          for (int mi = 0; mi < 4; mi++)
#pragma unroll
            for (int ni = 0; ni < 4; ni++) {
              const int d = cl + ni * 16 + l16;
              const float bv = bias[n0 + g * 128 + d];
              const int s0 = wm + mi * 16 + quad * 4;
              h4 pack;
#pragma unroll
              for (int r = 0; r < 4; r++) pack[r] = (_Float16)(acc[mi][ni][r] + bv);
              *(h4*)(&U[d * 136 + s0]) = pack;  // transposed: U[d][s]
            }
        } else {
#pragma unroll
          for (int mi = 0; mi < 4; mi++)
#pragma unroll
            for (int ni = 0; ni < 4; ni++) {
              const int d = cl + ni * 16 + l16;
              const float bv = bias[n0 + g * 128 + d];
#pragma unroll
              for (int r = 0; r < 4; r++) {
                const int s = wm + mi * 16 + quad * 4 + r;
                U[s * 136 + d] = (_Float16)(acc[mi][ni][r] + bv);
              }
            }
        }
      }
      __syncthreads();
      const int hh = ((n0 + g * 128) >> 7) & 15;
      const size_t hb = (size_t)bq * 16 + hh;
      if (which == 2) {
        _Float16* dst = vtp + hb * (size_t)(128 * 2048) + ms;
#pragma unroll
        for (int i = 0; i < 4; i++) {
          int f = i * 512 + tid, row = f >> 4, ch = f & 15;
          *(h8*)(dst + (size_t)row * 2048 + ch * 8) = *(h8*)(&U[row * 136 + ch * 8]);
        }
      } else {
        _Float16* dst = (which == 0 ? qp : kp) + (hb * 2048 + ms) * (size_t)128;
#pragma unroll
        for (int i = 0; i < 4; i++) {
          int f = i * 512 + tid, row = f >> 4, ch = f & 15;
          *(h8*)(dst + (size_t)row * 128 + ch * 8) = *(h8*)(&U[row * 136 + ch * 8]);
        }
      }
    }
  } else {
#pragma unroll
    for (int mi = 0; mi < 4; mi++)
#pragma unroll
      for (int ni = 0; ni < 4; ni++) {
        const int gm = m0 + wm + mi * 16 + quad * 4;
        const int gn = n0 + wn + ni * 16 + l16;
        const float bv = bias[gn];
#pragma unroll
        for (int r = 0; r < 4; r++) outp[(size_t)(gm + r) * N + gn] = acc[mi][ni][r] + bv;
      }
  }
}

// ---------------- fused causal ALiBi attention ----------------
// grid (32 bh, 16 px): 512 uniform blocks (2/CU, 2 waves/SIMD); same-(b,h) blocks share an
// XCD (linear id mod 8 = bh mod 8) so K/V re-reads hit that XCD's L2.
// Block: 4 waves x 16 q-rows = 64-row tile; pairs {31-px, px} -> 33 j-iters each.
// K/V async-DMA double-buffered (1 barrier/iter, latency hidden under compute).
// ALiBi as column bias slope*j (row term -slope*i cancels in softmax); causal mask only on
// the diagonal tile. Row-sum l via a ones-column MFMA tile (o[8]).
__global__ __launch_bounds__(256, 2) void attn_kernel(const _Float16* __restrict__ Q,
                                                      const _Float16* __restrict__ Kg,
                                                      const _Float16* __restrict__ Vt,
                                                      _Float16* __restrict__ ctx) {
  __shared__ _Float16 Ks[2][8192];   // 64 rows x 128, 16B-chunk XOR swizzle p = lc ^ (row&7)
  __shared__ _Float16 Vs[2][8192];   // 128 rows x 64, same swizzle
  __shared__ _Float16 Vones[1088];   // [16][68]: row 0 = ones (l-accumulator B-tile)
  __shared__ _Float16 Pl[4][16 * 68];  // per-wave P round-trip; stride 68 -> conflict-free

  const int bh = blockIdx.x, px = blockIdx.y;
  const int b = bh >> 4, h = bh & 15;
  const int tid = threadIdx.x, w = tid >> 6, lane = tid & 63, quad = lane >> 4, l16 = lane & 15;
  const size_t hbo = (size_t)bh * (2048 * 128);
  const _Float16* Qh = Q + hbo;
  const _Float16* Kh = Kg + hbo;
  const _Float16* Vh = Vt + hbo;
  const float slope = exp2f(-0.5f * (float)h);
  const float L2E = 1.44269504088896f;
  const float NEG = -3.0e38f;

  for (int i = tid; i < 1088; i += 256) Vones[i] = (_Float16)0.f;
  if (tid < 64) Vones[tid] = (_Float16)1.f;  // row 0, cols 0..63

  float cj[4];
  for (int jf = 0; jf < 4; jf++) cj[jf] = slope * (float)(jf * 16 + l16);

  // staging constants: K slot s=c*64+lane -> row=4c+quad, lc=l16^((c&1)*4+quad)
  //                    V slot s=c*64+lane -> row=8c+(lane>>3), lc=(lane&7)^(lane>>3)
  const int kle = (l16 ^ quad) * 8, klo = kle ^ 32;
  const int lq = lane >> 3, vlc = ((lane & 7) ^ lq) * 8;

  for (int phase = 0; phase < 2; phase++) {
    const int t = phase ? px : 31 - px;
    const int qbase = t * 64 + w * 16;

    h8 aq[4];  // Q A-frags: A[m=l16][k=quad*8+j] [m120-verified]
#pragma unroll
    for (int t4 = 0; t4 < 4; t4++)
      aq[t4] = *(const h8*)(Qh + (size_t)(qbase + l16) * 128 + t4 * 32 + quad * 8);

    f4 o[9] = {};  // o[0..7] = output tiles, o[8] = row-sum (ones column)
    float m_i[4];
    for (int r = 0; r < 4; r++) m_i[r] = NEG;

    const int jtiles = t + 1;
    __syncthreads();  // previous phase's buffer readers (and Vones init) done
    // stage tile 0 -> buf 0 (waves 0,1: K; waves 2,3: V)
    if (w < 2) {
      const _Float16* kb = Kh + (size_t)(32 * w + quad) * 128;
      _Float16* dst = &Ks[0][w * 4096];
#pragma unroll
      for (int cc = 0; cc < 8; cc++)
        load_lds16(kb + (size_t)(4 * cc) * 128 + ((cc & 1) ? klo : kle), dst + cc * 512);
    } else {
      const _Float16* vb = Vh + (size_t)(64 * (w - 2) + lq) * 2048 + vlc;
      _Float16* dst = &Vs[0][(w - 2) * 4096];
#pragma unroll
      for (int cc = 0; cc < 8; cc++) load_lds16(vb + (size_t)(8 * cc) * 2048, dst + cc * 512);
    }

    for (int jt = 0; jt < jtiles; jt++) {
      const int j0 = jt * 64, cur = jt & 1;
      __syncthreads();  // buf[cur] staged (each wave drains vmcnt before barrier)
      if (jt + 1 < jtiles) {  // async-stage next tile into back buffer
        const int nj0 = j0 + 64, nb = cur ^ 1;
        if (w < 2) {
          const _Float16* kb = Kh + (size_t)(nj0 + 32 * w + quad) * 128;
          _Float16* dst = &Ks[nb][w * 4096];
#pragma unroll
          for (int cc = 0; cc < 8; cc++)
            load_lds16(kb + (size_t)(4 * cc) * 128 + ((cc & 1) ? klo : kle), dst + cc * 512);
        } else {
          const _Float16* vb = Vh + (size_t)(64 * (w - 2) + lq) * 2048 + nj0 + vlc;
          _Float16* dst = &Vs[nb][(w - 2) * 4096];
#pragma unroll
          for (int cc = 0; cc < 8; cc++) load_lds16(vb + (size_t)(8 * cc) * 2048, dst + cc * 512);
        }
      }
      // S = Q K^T (B-frag from swizzled Ks)
      f4 sc[4] = {};
#pragma unroll
      for (int jf = 0; jf < 4; jf++) {
        const int row = jf * 16 + l16;
#pragma unroll
        for (int t4 = 0; t4 < 4; t4++) {
          const int p = (t4 * 4 + quad) ^ (l16 & 7);
          h8 bk = *(const h8*)(&Ks[cur][row * 128 + p * 8]);
          sc[jf] = MFMA16(aq[t4], bk, sc[jf]);
        }
      }
      // ALiBi column bias
      const float bj0 = slope * (float)j0;
#pragma unroll
      for (int jf = 0; jf < 4; jf++) {
        const float cb = bj0 + cj[jf];
#pragma unroll
        for (int r = 0; r < 4; r++) sc[jf][r] += cb;
      }
      if (jt == jtiles - 1) {  // diagonal tile: causal mask
#pragma unroll
        for (int jf = 0; jf < 4; jf++) {
          const int j = j0 + jf * 16 + l16;
#pragma unroll
          for (int r = 0; r < 4; r++)
            if (j > qbase + quad * 4 + r) sc[jf][r] = NEG;
        }
      }
      // online softmax (max only; sum rides in o[8])
      float m_new[4], alpha[4];
#pragma unroll
      for (int r = 0; r < 4; r++) {
        float v = fmaxf(fmaxf(sc[0][r], sc[1][r]), fmaxf(sc[2][r], sc[3][r]));
        v = fmaxf(v, __shfl_xor(v, 1));
        v = fmaxf(v, __shfl_xor(v, 2));
        v = fmaxf(v, __shfl_xor(v, 4));
        v = fmaxf(v, __shfl_xor(v, 8));
        m_new[r] = fmaxf(m_i[r], v);
        alpha[r] = exp2f((m_i[r] - m_new[r]) * L2E);
        m_i[r] = m_new[r];
      }
#pragma unroll
      for (int jf = 0; jf < 4; jf++)
#pragma unroll
        for (int r = 0; r < 4; r++) sc[jf][r] = exp2f((sc[jf][r] - m_new[r]) * L2E);
#pragma unroll
      for (int nt = 0; nt < 9; nt++)
#pragma unroll
        for (int r = 0; r < 4; r++) o[nt][r] *= alpha[r];
      // P: C-layout -> A-layout via per-wave LDS (stride 68: conflict-free writes)
#pragma unroll
      for (int jf = 0; jf < 4; jf++)
#pragma unroll
        for (int r = 0; r < 4; r++)
          Pl[w][(quad * 4 + r) * 68 + jf * 16 + l16] = (_Float16)sc[jf][r];
      asm volatile("s_waitcnt lgkmcnt(0)" ::: "memory");
      h8 ap0 = *(const h8*)(&Pl[w][l16 * 68 + quad * 8]);
      h8 ap1 = *(const h8*)(&Pl[w][l16 * 68 + 32 + quad * 8]);
      // O += P V (B-frag from swizzled Vs) + ones-tile for l
#pragma unroll
      for (int nt = 0; nt < 8; nt++) {
        const int row = nt * 16 + l16;
        const int p0 = quad ^ (l16 & 7), p1 = (4 + quad) ^ (l16 & 7);
        h8 bv0 = *(const h8*)(&Vs[cur][row * 64 + p0 * 8]);
        h8 bv1 = *(const h8*)(&Vs[cur][row * 64 + p1 * 8]);
        o[nt] = MFMA16(ap0, bv0, o[nt]);
        o[nt] = MFMA16(ap1, bv1, o[nt]);
      }
      {
        h8 b0 = *(const h8*)(&Vones[l16 * 68 + quad * 8]);
        h8 b1 = *(const h8*)(&Vones[l16 * 68 + 32 + quad * 8]);
        o[8] = MFMA16(ap0, b0, o[8]);
        o[8] = MFMA16(ap1, b1, o[8]);
      }
    }

    // epilogue: l = o[8] col 0 (broadcast within quad), normalize, write ctx
#pragma unroll
    for (int r = 0; r < 4; r++) {
      float lsum = __shfl(o[8][r], lane & 48);
      float inv = 1.0f / lsum;
      const int i = qbase + quad * 4 + r;
      const size_t row = (size_t)b * 2048 + i;
#pragma unroll
      for (int nt = 0; nt < 8; nt++)
        ctx[row * 2048 + h * 128 + nt * 16 + l16] = (_Float16)(o[nt][r] * inv);
    }
  }
}

extern "C" void kernel_launch(void* const* d_in, const int* in_sizes, int n_in, void* d_out,
                              int out_size, void* d_ws, size_t ws_size, hipStream_t stream) {
  const float* x = (const float*)d_in[0];      // [2,2048,2048]
  const float* qkv_w = (const float*)d_in[1];  // [2048,6144]
  const float* qkv_b = (const float*)d_in[2];  // [6144]
  const float* out_w = (const float*)d_in[3];  // [2048,2048]
  const float* out_b = (const float*)d_in[4];  // [2048]
  float* out = (float*)d_out;                  // [4096,2048] f32

  char* ws = (char*)d_ws;
  if (ws_size < 117440512u) return;  // need 112 MiB
  _Float16* xb  = (_Float16*)(ws + 0);          // 16 MiB  [4096][2048]
  _Float16* wqt = (_Float16*)(ws + 16777216);   // 24 MiB  [6144][2048]
  _Float16* wot = (_Float16*)(ws + 41943040);   // 8 MiB   [2048][2048]
  _Float16* q   = (_Float16*)(ws + 50331648);   // 16 MiB  [b,h,s,d]
  _Float16* k   = (_Float16*)(ws + 67108864);   // 16 MiB  [b,h,s,d]
  _Float16* vt  = (_Float16*)(ws + 83886080);   // 16 MiB  [b,h,d,s]
  _Float16* ctx = (_Float16*)(ws + 100663296);  // 16 MiB  [4096][2048]

  cvt_f32_f16<<<8192, 256, 0, stream>>>(x, xb, 8388608);
  transpose_cvt<<<dim3(96, 32), 256, 0, stream>>>(qkv_w, wqt, 2048, 6144);
  transpose_cvt<<<dim3(32, 32), 256, 0, stream>>>(out_w, wot, 2048, 2048);
  gemm_pipe<0><<<dim3(24, 32), 512, 0, stream>>>(xb, wqt, qkv_b, 2048, q, k, vt, nullptr, 6144);
  attn_kernel<<<dim3(32, 16), 256, 0, stream>>>(q, k, vt, ctx);
  gemm_pipe<1><<<dim3(8, 32), 512, 0, stream>>>(ctx, wot, out_b, 2048, nullptr, nullptr, nullptr,
                                                out, 2048);
}